// Round 5
// baseline (353.332 us; speedup 1.0000x reference)
//
#include <hip/hip_runtime.h>
#include <math.h>

#define N_ 64
#define C_ 128
#define K_ 64
#define P_ 4096
#define PT 32
#define TILES_PER_N 16
#define PB (P_ / TILES_PER_N)   // 256
#define NSUB (PB / PT)          // 8

typedef __attribute__((ext_vector_type(8))) short short8;
typedef __attribute__((ext_vector_type(4))) float f32x4;

union U4S8 { uint4 u4; unsigned int u[4]; short8 s; };

// (hi bf16 of a) in low16, (hi bf16 of b) in high16 — MFMA k-pair order
__device__ __forceinline__ unsigned int pair_hi(float a, float b) {
    return (__float_as_uint(b) & 0xffff0000u) | (__float_as_uint(a) >> 16);
}
__device__ __forceinline__ float lo_part(float f) {
    return f - __uint_as_float(__float_as_uint(f) & 0xffff0000u);
}

#define MFMA16(a, b, c) __builtin_amdgcn_mfma_f32_16x16x32_bf16(a, b, c, 0, 0, 0)

// swizzle mask for the x [p][c] planes
__device__ __forceinline__ int pmask(int p) { return (p & 7) ^ ((p >> 3) & 3); }

__global__ __launch_bounds__(256, 3)
void netvlad_main(const float* __restrict__ x,
                  const float* __restrict__ conv_w,
                  const float* __restrict__ conv_b,
                  float* __restrict__ acc_part,
                  float* __restrict__ asum_part,
                  int use_atomic)
{
    __shared__ unsigned int xhi [PT * 64];   // 8 KB  [p][c-pair], chunk-XOR pmask(p)
    __shared__ unsigned int xlo [PT * 64];   // 8 KB
    __shared__ unsigned int xthi[C_ * 20];   // 10 KB [c][p-pair], stride 20
    __shared__ unsigned int xtlo[C_ * 20];   // 10 KB
    __shared__ unsigned int ahi_[K_ * 20];   // 5 KB  [k][p-pair], stride 20, chunk-XOR
    __shared__ unsigned int alo_[K_ * 20];   // 5 KB
    __shared__ float        red2[PT * 4];    // 0.5 KB [p][wave] ssq partials
    __shared__ float2       stats[PT * 2];   // 0.5 KB [p][mth] (max,sum)
    __shared__ float        fredw[2 * K_];   // 0.5 KB [ntp][k] asum partials

    const int t  = threadIdx.x;
    const int wv = t >> 6;
    const int l  = t & 63;
    const int n    = blockIdx.x >> 4;
    const int tile = blockIdx.x & 15;

    const int mrow = l & 15;     // MFMA m/n lane index
    const int kq   = l >> 4;     // MFMA k-quad

    // staging: thread owns c in {4cq..4cq+3}, p in {4ppq..4ppq+3}
    const int ppq = t & 7;
    const int cq  = t >> 3;      // 0..31

    // phase A / softmax: wave -> p-half ntp, k-half mth; lane column:
    const int ntp = wv & 1;
    const int mth = wv >> 1;
    const int mt0 = 2 * mth;
    const int pcol = ntp * 16 + mrow;

    // ---- conv_w fragments resident in registers for the wave's two m-tiles ----
    short8 whi[2][4], wlo[2][4];
    #pragma unroll
    for (int mtl = 0; mtl < 2; ++mtl) {
        const float* wr = conv_w + (size_t)((mt0 + mtl) * 16 + mrow) * C_;
        #pragma unroll
        for (int s = 0; s < 4; ++s) {
            U4S8 h, lo;
            #pragma unroll
            for (int j = 0; j < 4; ++j) {
                float f0 = wr[s * 32 + kq * 8 + 2 * j];
                float f1 = wr[s * 32 + kq * 8 + 2 * j + 1];
                h.u[j]  = pair_hi(f0, f1);
                lo.u[j] = pair_hi(lo_part(f0), lo_part(f1));
            }
            whi[mtl][s] = h.s; wlo[mtl][s] = lo.s;
        }
    }
    // this lane's 8 fixed k-slots: k_i = 32*mth + 16*(i>>2) + 4*kq + (i&3)
    float cb8[8];
    #pragma unroll
    for (int i = 0; i < 8; ++i)
        cb8[i] = conv_b[32 * mth + 16 * (i >> 2) + 4 * kq + (i & 3)];

    f32x4 accC[4][2];
    #pragma unroll
    for (int mt = 0; mt < 4; ++mt)
        #pragma unroll
        for (int ntl = 0; ntl < 2; ++ntl) accC[mt][ntl] = (f32x4){0.f, 0.f, 0.f, 0.f};
    float asum_acc[8];
    #pragma unroll
    for (int i = 0; i < 8; ++i) asum_acc[i] = 0.f;

    const float* xb = x + ((size_t)n * C_) * P_ + tile * PB + 4 * ppq;

    float4 ld[4];
    #pragma unroll
    for (int cc = 0; cc < 4; ++cc)
        ld[cc] = *(const float4*)(xb + (size_t)(4 * cq + cc) * P_);

    for (int sub = 0; sub < NSUB; ++sub) {
        __syncthreads();   // (1) LDS free of previous-iteration readers

        // ---- stage both layouts (hi/lo planes) + column-norm partials ----
        {
            const float* lf = (const float*)ld;   // lf[cc*4+j]
            #pragma unroll
            for (int cc = 0; cc < 4; ++cc) {
                float4 v = ld[cc];
                int c = 4 * cq + cc;
                uint2 wh; wh.x = pair_hi(v.x, v.y); wh.y = pair_hi(v.z, v.w);
                *(uint2*)(xthi + c * 20 + 2 * ppq) = wh;
                uint2 wl; wl.x = pair_hi(lo_part(v.x), lo_part(v.y));
                wl.y = pair_hi(lo_part(v.z), lo_part(v.w));
                *(uint2*)(xtlo + c * 20 + 2 * ppq) = wl;
            }
            float ssq[4];
            #pragma unroll
            for (int j = 0; j < 4; ++j) {
                int p = 4 * ppq + j;
                int ch = cq >> 1;
                int chp = (ch & 8) | ((ch ^ pmask(p)) & 7);
                int base = p * 64 + (chp << 2) + ((cq & 1) << 1);
                float f0 = lf[0 * 4 + j], f1 = lf[1 * 4 + j];
                float f2 = lf[2 * 4 + j], f3 = lf[3 * 4 + j];
                uint2 wh; wh.x = pair_hi(f0, f1); wh.y = pair_hi(f2, f3);
                *(uint2*)(xhi + base) = wh;
                uint2 wl; wl.x = pair_hi(lo_part(f0), lo_part(f1));
                wl.y = pair_hi(lo_part(f2), lo_part(f3));
                *(uint2*)(xlo + base) = wl;
                ssq[j] = f0 * f0 + f1 * f1 + f2 * f2 + f3 * f3;
            }
            #pragma unroll
            for (int j = 0; j < 4; ++j) {
                ssq[j] += __shfl_xor(ssq[j], 8);
                ssq[j] += __shfl_xor(ssq[j], 16);
                ssq[j] += __shfl_xor(ssq[j], 32);
            }
            if (l < 8) {
                #pragma unroll
                for (int j = 0; j < 4; ++j)
                    red2[(4 * (l & 7) + j) * 4 + wv] = ssq[j];
            }
        }
        // prefetch next subtile
        if (sub + 1 < NSUB) {
            #pragma unroll
            for (int cc = 0; cc < 4; ++cc)
                ld[cc] = *(const float4*)(xb + (size_t)(4 * cq + cc) * P_ + (sub + 1) * PT);
        }
        __syncthreads();   // (2) staged

        // per-lane column norm for this lane's column
        float4 rr = *(const float4*)(red2 + pcol * 4);
        float rnv = 1.f / fmaxf(sqrtf(rr.x + rr.y + rr.z + rr.w), 1e-12f);

        // ---- phase A: raw logits in registers (3-term split), B-frag shared ----
        f32x4 a0 = (f32x4){0.f, 0.f, 0.f, 0.f};
        f32x4 a1 = (f32x4){0.f, 0.f, 0.f, 0.f};
        {
            const int msk = pmask(pcol);
            #pragma unroll
            for (int s = 0; s < 4; ++s) {
                int ch = s * 4 + kq;
                int chp = (ch & 8) | ((ch ^ msk) & 7);
                int idx = pcol * 64 + (chp << 2);
                U4S8 bh, bl;
                bh.u4 = *(const uint4*)(xhi + idx);
                bl.u4 = *(const uint4*)(xlo + idx);
                a0 = MFMA16(whi[0][s], bh.s, a0);
                a0 = MFMA16(whi[0][s], bl.s, a0);
                a0 = MFMA16(wlo[0][s], bh.s, a0);
                a1 = MFMA16(whi[1][s], bh.s, a1);
                a1 = MFMA16(whi[1][s], bl.s, a1);
                a1 = MFMA16(wlo[1][s], bh.s, a1);
            }
        }

        // ---- softmax stats over this wave's 32 k's (in-register) ----
        float lv[8];
        #pragma unroll
        for (int r = 0; r < 4; ++r) { lv[r] = a0[r] * rnv + cb8[r]; }
        #pragma unroll
        for (int r = 0; r < 4; ++r) { lv[4 + r] = a1[r] * rnv + cb8[4 + r]; }
        float m = lv[0];
        #pragma unroll
        for (int i = 1; i < 8; ++i) m = fmaxf(m, lv[i]);
        float s = 0.f;
        #pragma unroll
        for (int i = 0; i < 8; ++i) s += __expf(lv[i] - m);
        #pragma unroll
        for (int off = 16; off <= 32; off <<= 1) {
            float mo = __shfl_xor(m, off);
            float so = __shfl_xor(s, off);
            float Mn = fmaxf(m, mo);
            s = s * __expf(m - Mn) + so * __expf(mo - Mn);
            m = Mn;
        }
        if (kq == 0) stats[pcol * 2 + mth] = make_float2(m, s);
        __syncthreads();   // (3) stats ready

        // ---- combine halves, exponentiate own registers, write packed a·rn ----
        {
            float4 st = *(const float4*)(stats + pcol * 2);  // (m0,s0,m1,s1)
            float M = fmaxf(st.x, st.z);
            float S = st.y * __expf(st.x - M) + st.w * __expf(st.z - M);
            float inv = 1.f / S;
            const int p2 = 8 * ntp + (mrow >> 1);
            #pragma unroll
            for (int i = 0; i < 8; ++i) {
                float a = __expf(lv[i] - M) * inv;
                asum_acc[i] += a;
                float av = a * rnv;
                float pav = __shfl_xor(av, 1);
                if ((mrow & 1) == 0) {
                    int k = 32 * mth + 16 * (i >> 2) + 4 * kq + (i & 3);
                    int chp = (p2 >> 2) ^ ((k >> 3) & 3);
                    int off = k * 20 + (chp << 2) + (p2 & 3);
                    ahi_[off] = pair_hi(av, pav);
                    alo_[off] = pair_hi(lo_part(av), lo_part(pav));
                }
            }
        }
        __syncthreads();   // (4) packed a ready

        // ---- phase C: accC[k][c] += a_scaled · x (3-term split) ----
        {
            U4S8 ah[4], al[4];
            #pragma unroll
            for (int mt = 0; mt < 4; ++mt) {
                int ar = mt * 16 + mrow;
                int chp = kq ^ ((ar >> 3) & 3);
                int idx = ar * 20 + (chp << 2);
                ah[mt].u4 = *(const uint4*)(ahi_ + idx);
                al[mt].u4 = *(const uint4*)(alo_ + idx);
            }
            #pragma unroll
            for (int ntl = 0; ntl < 2; ++ntl) {
                int cr = (2 * wv + ntl) * 16 + mrow;
                int xi = cr * 20 + kq * 4;
                U4S8 xh, xl2;
                xh.u4  = *(const uint4*)(xthi + xi);
                xl2.u4 = *(const uint4*)(xtlo + xi);
                #pragma unroll
                for (int mt = 0; mt < 4; ++mt) {
                    accC[mt][ntl] = MFMA16(ah[mt].s, xh.s,  accC[mt][ntl]);
                    accC[mt][ntl] = MFMA16(ah[mt].s, xl2.s, accC[mt][ntl]);
                    accC[mt][ntl] = MFMA16(al[mt].s, xh.s,  accC[mt][ntl]);
                }
            }
        }
    }

    __syncthreads();
    // ---- asum: reduce over the wave's 16 columns, stage per (ntp,k) ----
    #pragma unroll
    for (int i = 0; i < 8; ++i) {
        asum_acc[i] += __shfl_xor(asum_acc[i], 1);
        asum_acc[i] += __shfl_xor(asum_acc[i], 2);
        asum_acc[i] += __shfl_xor(asum_acc[i], 4);
        asum_acc[i] += __shfl_xor(asum_acc[i], 8);
    }
    if (mrow == 0) {
        #pragma unroll
        for (int i = 0; i < 8; ++i) {
            int k = 32 * mth + 16 * (i >> 2) + 4 * kq + (i & 3);
            fredw[ntp * K_ + k] = asum_acc[i];
        }
    }
    // ---- flush accC (D layout: m = mt*16+kq*4+r, n = (2wv+ntl)*16+mrow) ----
    if (!use_atomic) {
        float* dst = acc_part + (size_t)blockIdx.x * K_ * C_;
        #pragma unroll
        for (int mt = 0; mt < 4; ++mt)
            #pragma unroll
            for (int r = 0; r < 4; ++r)
                #pragma unroll
                for (int ntl = 0; ntl < 2; ++ntl)
                    dst[(mt * 16 + kq * 4 + r) * C_ + (2 * wv + ntl) * 16 + mrow] =
                        accC[mt][ntl][r];
    } else {
        float* dst = acc_part + (size_t)n * K_ * C_;
        #pragma unroll
        for (int mt = 0; mt < 4; ++mt)
            #pragma unroll
            for (int r = 0; r < 4; ++r)
                #pragma unroll
                for (int ntl = 0; ntl < 2; ++ntl)
                    atomicAdd(dst + (mt * 16 + kq * 4 + r) * C_ + (2 * wv + ntl) * 16 + mrow,
                              accC[mt][ntl][r]);
    }
    __syncthreads();
    if (t < K_) {
        float v = fredw[t] + fredw[K_ + t];
        if (use_atomic) atomicAdd(asum_part + n * K_ + t, v);
        else            asum_part[(size_t)blockIdx.x * K_ + t] = v;
    }
}

// ---------------------------------------------------------------------------
// Finalize: reduce npart slices, vlad = acc - asum*centroid, intra-norm over C,
// global norm, store. One block per n; thread t owns (k=t/4, c-quarter=t%4).
// ---------------------------------------------------------------------------
__global__ __launch_bounds__(256, 4)
void netvlad_finalize(const float* __restrict__ acc_part,
                      const float* __restrict__ asum_part,
                      const float* __restrict__ centroids,
                      float* __restrict__ out,
                      int npart)
{
    __shared__ float wred[4];
    const int t = threadIdx.x;
    const int n = blockIdx.x;
    const int k = t >> 2;
    const int part = t & 3;

    float a_k = 0.f;
    for (int s = 0; s < npart; ++s)
        a_k += asum_part[(size_t)(n * npart + s) * K_ + k];

    float4 vals[8];
    #pragma unroll
    for (int i = 0; i < 8; ++i) vals[i] = make_float4(0.f, 0.f, 0.f, 0.f);
    for (int s = 0; s < npart; ++s) {
        const float4* av = (const float4*)(acc_part
            + ((size_t)(n * npart + s) * K_ + k) * C_ + part * 32);
        #pragma unroll
        for (int i = 0; i < 8; ++i) {
            float4 a = av[i];
            vals[i].x += a.x; vals[i].y += a.y;
            vals[i].z += a.z; vals[i].w += a.w;
        }
    }

    const float4* cenv = (const float4*)(centroids + k * C_ + part * 32);
    float loc = 0.f;
    #pragma unroll
    for (int i = 0; i < 8; ++i) {
        float4 cv = cenv[i];
        float4 v = vals[i];
        v.x -= a_k * cv.x; v.y -= a_k * cv.y;
        v.z -= a_k * cv.z; v.w -= a_k * cv.w;
        vals[i] = v;
        loc += v.x * v.x + v.y * v.y + v.z * v.z + v.w * v.w;
    }
    loc += __shfl_xor(loc, 1);
    loc += __shfl_xor(loc, 2);
    float rk = 1.f / fmaxf(sqrtf(loc), 1e-12f);

    float tot = 0.f;
    #pragma unroll
    for (int i = 0; i < 8; ++i) {
        float4 v = vals[i];
        v.x *= rk; v.y *= rk; v.z *= rk; v.w *= rk;
        vals[i] = v;
        tot += v.x * v.x + v.y * v.y + v.z * v.z + v.w * v.w;
    }
    #pragma unroll
    for (int o = 1; o < 64; o <<= 1) tot += __shfl_xor(tot, o);
    if ((t & 63) == 0) wred[t >> 6] = tot;
    __syncthreads();
    float T = wred[0] + wred[1] + wred[2] + wred[3];
    float rtot = 1.f / fmaxf(sqrtf(T), 1e-12f);

    float4* outv = (float4*)(out + ((size_t)n * K_ + k) * C_ + part * 32);
    #pragma unroll
    for (int i = 0; i < 8; ++i) {
        float4 v = vals[i];
        v.x *= rtot; v.y *= rtot; v.z *= rtot; v.w *= rtot;
        outv[i] = v;
    }
}

extern "C" void kernel_launch(void* const* d_in, const int* in_sizes, int n_in,
                              void* d_out, int out_size, void* d_ws, size_t ws_size,
                              hipStream_t stream)
{
    const float* x      = (const float*)d_in[0];
    // d_in[1] = xyz — unused by the reference computation
    const float* cent   = (const float*)d_in[2];
    const float* conv_w = (const float*)d_in[3];
    const float* conv_b = (const float*)d_in[4];
    float* out = (float*)d_out;

    const int nblk = N_ * TILES_PER_N;   // 1024
    size_t need = (size_t)nblk * K_ * C_ * sizeof(float)
                + (size_t)nblk * K_ * sizeof(float);
    int use_atomic = (ws_size >= need) ? 0 : 1;
    int npart = use_atomic ? 1 : TILES_PER_N;

    float* acc_part  = (float*)d_ws;
    float* asum_part = acc_part + (size_t)(use_atomic ? N_ : nblk) * K_ * C_;

    if (use_atomic) {
        size_t zbytes = ((size_t)N_ * K_ * C_ + (size_t)N_ * K_) * sizeof(float);
        hipMemsetAsync(d_ws, 0, zbytes, stream);
    }

    hipLaunchKernelGGL(netvlad_main, dim3(nblk), dim3(256), 0, stream,
                       x, conv_w, conv_b, acc_part, asum_part, use_atomic);
    hipLaunchKernelGGL(netvlad_finalize, dim3(N_), dim3(256), 0, stream,
                       acc_part, asum_part, cent, out, npart);
}

// Round 6
// 220.466 us; speedup vs baseline: 1.6027x; 1.6027x over previous
//
#include <hip/hip_runtime.h>
#include <math.h>

#define N_ 64
#define C_ 128
#define K_ 64
#define P_ 4096
#define PT 32
#define TILES_PER_N 8
#define PB (P_ / TILES_PER_N)   // 512
#define NSUB (PB / PT)          // 16

typedef __attribute__((ext_vector_type(8))) short short8;
typedef __attribute__((ext_vector_type(4))) float f32x4;

union U4S8 { uint4 u4; unsigned int u[4]; short8 s; };

// (hi bf16 of a) in low16, (hi bf16 of b) in high16 — MFMA k-pair order
__device__ __forceinline__ unsigned int pair_hi(float a, float b) {
    return (__float_as_uint(b) & 0xffff0000u) | (__float_as_uint(a) >> 16);
}
__device__ __forceinline__ float lo_part(float f) {
    return f - __uint_as_float(__float_as_uint(f) & 0xffff0000u);
}

#define MFMA16(a, b, c) __builtin_amdgcn_mfma_f32_16x16x32_bf16(a, b, c, 0, 0, 0)

// swizzle mask for the x [p][c] planes
__device__ __forceinline__ int pmask(int p) { return (p & 7) ^ ((p >> 3) & 3); }

__global__ __launch_bounds__(256, 2)
void netvlad_main(const float* __restrict__ x,
                  const float* __restrict__ conv_w,
                  const float* __restrict__ conv_b,
                  float* __restrict__ acc_part,
                  float* __restrict__ asum_part,
                  int use_atomic)
{
    __shared__ unsigned int xhi [PT * 64];   // 8 KB  [p][c-pair], chunk-XOR pmask(p)
    __shared__ unsigned int xlo [PT * 64];   // 8 KB
    __shared__ unsigned int xthi[C_ * 20];   // 10 KB [c][p-pair], stride 20
    __shared__ unsigned int xtlo[C_ * 20];   // 10 KB
    __shared__ unsigned int ahi_[K_ * 20];   // 5 KB  [k][p-pair], stride 20, chunk-XOR
    __shared__ unsigned int alo_[K_ * 20];   // 5 KB
    __shared__ float        red2[PT * 4];    // 0.5 KB [p][wave] ssq partials
    __shared__ float2       stats[PT * 2];   // 0.5 KB [p][mth] (max,sum)
    __shared__ float        fredw[2 * K_];   // 0.5 KB [ntp][k] asum partials

    const int t  = threadIdx.x;
    const int wv = t >> 6;
    const int l  = t & 63;
    const int n    = blockIdx.x >> 3;
    const int tile = blockIdx.x & 7;

    const int mrow = l & 15;     // MFMA m/n lane index
    const int kq   = l >> 4;     // MFMA k-quad

    // staging: thread owns c in {4cq..4cq+3}, p in {4ppq..4ppq+3}
    const int ppq = t & 7;
    const int cq  = t >> 3;      // 0..31

    // phase A / softmax: wave -> p-half ntp, k-half mth; lane column:
    const int ntp = wv & 1;
    const int mth = wv >> 1;
    const int mt0 = 2 * mth;
    const int pcol = ntp * 16 + mrow;

    // ---- conv_w fragments resident in registers for the wave's two m-tiles ----
    short8 whi[2][4], wlo[2][4];
    #pragma unroll
    for (int mtl = 0; mtl < 2; ++mtl) {
        const float* wr = conv_w + (size_t)((mt0 + mtl) * 16 + mrow) * C_;
        #pragma unroll
        for (int s = 0; s < 4; ++s) {
            float4 v0 = *(const float4*)(wr + s * 32 + kq * 8);
            float4 v1 = *(const float4*)(wr + s * 32 + kq * 8 + 4);
            U4S8 h, lo;
            h.u[0]  = pair_hi(v0.x, v0.y);
            h.u[1]  = pair_hi(v0.z, v0.w);
            h.u[2]  = pair_hi(v1.x, v1.y);
            h.u[3]  = pair_hi(v1.z, v1.w);
            lo.u[0] = pair_hi(lo_part(v0.x), lo_part(v0.y));
            lo.u[1] = pair_hi(lo_part(v0.z), lo_part(v0.w));
            lo.u[2] = pair_hi(lo_part(v1.x), lo_part(v1.y));
            lo.u[3] = pair_hi(lo_part(v1.z), lo_part(v1.w));
            whi[mtl][s] = h.s; wlo[mtl][s] = lo.s;
        }
    }
    // this lane's 8 fixed k-slots: k_i = 32*mth + 16*(i>>2) + 4*kq + (i&3)
    float cb8[8];
    #pragma unroll
    for (int i = 0; i < 8; ++i)
        cb8[i] = conv_b[32 * mth + 16 * (i >> 2) + 4 * kq + (i & 3)];

    f32x4 accC[4][2];
    #pragma unroll
    for (int mt = 0; mt < 4; ++mt)
        #pragma unroll
        for (int ntl = 0; ntl < 2; ++ntl) accC[mt][ntl] = (f32x4){0.f, 0.f, 0.f, 0.f};
    float asum_acc[8];
    #pragma unroll
    for (int i = 0; i < 8; ++i) asum_acc[i] = 0.f;

    const float* xb = x + ((size_t)n * C_) * P_ + tile * PB + 4 * ppq;

    float4 ld[4];
    #pragma unroll
    for (int cc = 0; cc < 4; ++cc)
        ld[cc] = *(const float4*)(xb + (size_t)(4 * cq + cc) * P_);

    for (int sub = 0; sub < NSUB; ++sub) {
        __syncthreads();   // (1) LDS free of previous-iteration readers

        // ---- stage both layouts (hi/lo planes) + column-norm partials ----
        {
            const float* lf = (const float*)ld;   // lf[cc*4+j]
            #pragma unroll
            for (int cc = 0; cc < 4; ++cc) {
                float4 v = ld[cc];
                int c = 4 * cq + cc;
                uint2 wh; wh.x = pair_hi(v.x, v.y); wh.y = pair_hi(v.z, v.w);
                *(uint2*)(xthi + c * 20 + 2 * ppq) = wh;
                uint2 wl; wl.x = pair_hi(lo_part(v.x), lo_part(v.y));
                wl.y = pair_hi(lo_part(v.z), lo_part(v.w));
                *(uint2*)(xtlo + c * 20 + 2 * ppq) = wl;
            }
            float ssq[4];
            #pragma unroll
            for (int j = 0; j < 4; ++j) {
                int p = 4 * ppq + j;
                int ch = cq >> 1;
                int chp = (ch & 8) | ((ch ^ pmask(p)) & 7);
                int base = p * 64 + (chp << 2) + ((cq & 1) << 1);
                float f0 = lf[0 * 4 + j], f1 = lf[1 * 4 + j];
                float f2 = lf[2 * 4 + j], f3 = lf[3 * 4 + j];
                uint2 wh; wh.x = pair_hi(f0, f1); wh.y = pair_hi(f2, f3);
                *(uint2*)(xhi + base) = wh;
                uint2 wl; wl.x = pair_hi(lo_part(f0), lo_part(f1));
                wl.y = pair_hi(lo_part(f2), lo_part(f3));
                *(uint2*)(xlo + base) = wl;
                ssq[j] = f0 * f0 + f1 * f1 + f2 * f2 + f3 * f3;
            }
            #pragma unroll
            for (int j = 0; j < 4; ++j) {
                ssq[j] += __shfl_xor(ssq[j], 8);
                ssq[j] += __shfl_xor(ssq[j], 16);
                ssq[j] += __shfl_xor(ssq[j], 32);
            }
            if (l < 8) {
                #pragma unroll
                for (int j = 0; j < 4; ++j)
                    red2[(4 * (l & 7) + j) * 4 + wv] = ssq[j];
            }
        }
        // prefetch next subtile
        if (sub + 1 < NSUB) {
            #pragma unroll
            for (int cc = 0; cc < 4; ++cc)
                ld[cc] = *(const float4*)(xb + (size_t)(4 * cq + cc) * P_ + (sub + 1) * PT);
        }
        __syncthreads();   // (2) staged

        // per-lane column norm for this lane's column
        float4 rr = *(const float4*)(red2 + pcol * 4);
        float rnv = 1.f / fmaxf(sqrtf(rr.x + rr.y + rr.z + rr.w), 1e-12f);

        // ---- phase A: raw logits in registers (3-term split), B-frag shared ----
        f32x4 a0 = (f32x4){0.f, 0.f, 0.f, 0.f};
        f32x4 a1 = (f32x4){0.f, 0.f, 0.f, 0.f};
        {
            const int msk = pmask(pcol);
            #pragma unroll
            for (int s = 0; s < 4; ++s) {
                int ch = s * 4 + kq;
                int chp = (ch & 8) | ((ch ^ msk) & 7);
                int idx = pcol * 64 + (chp << 2);
                U4S8 bh, bl;
                bh.u4 = *(const uint4*)(xhi + idx);
                bl.u4 = *(const uint4*)(xlo + idx);
                a0 = MFMA16(whi[0][s], bh.s, a0);
                a0 = MFMA16(whi[0][s], bl.s, a0);
                a0 = MFMA16(wlo[0][s], bh.s, a0);
                a1 = MFMA16(whi[1][s], bh.s, a1);
                a1 = MFMA16(whi[1][s], bl.s, a1);
                a1 = MFMA16(wlo[1][s], bh.s, a1);
            }
        }

        // ---- softmax stats over this wave's 32 k's (in-register) ----
        float lv[8];
        #pragma unroll
        for (int r = 0; r < 4; ++r) { lv[r] = a0[r] * rnv + cb8[r]; }
        #pragma unroll
        for (int r = 0; r < 4; ++r) { lv[4 + r] = a1[r] * rnv + cb8[4 + r]; }
        float m = lv[0];
        #pragma unroll
        for (int i = 1; i < 8; ++i) m = fmaxf(m, lv[i]);
        float s = 0.f;
        #pragma unroll
        for (int i = 0; i < 8; ++i) s += __expf(lv[i] - m);
        #pragma unroll
        for (int off = 16; off <= 32; off <<= 1) {
            float mo = __shfl_xor(m, off);
            float so = __shfl_xor(s, off);
            float Mn = fmaxf(m, mo);
            s = s * __expf(m - Mn) + so * __expf(mo - Mn);
            m = Mn;
        }
        if (kq == 0) stats[pcol * 2 + mth] = make_float2(m, s);
        __syncthreads();   // (3) stats ready

        // ---- combine halves, exponentiate own registers, write packed a·rn ----
        {
            float4 st = *(const float4*)(stats + pcol * 2);  // (m0,s0,m1,s1)
            float M = fmaxf(st.x, st.z);
            float S = st.y * __expf(st.x - M) + st.w * __expf(st.z - M);
            float inv = 1.f / S;
            const int p2 = 8 * ntp + (mrow >> 1);
            #pragma unroll
            for (int i = 0; i < 8; ++i) {
                float a = __expf(lv[i] - M) * inv;
                asum_acc[i] += a;
                float av = a * rnv;
                float pav = __shfl_xor(av, 1);
                if ((mrow & 1) == 0) {
                    int k = 32 * mth + 16 * (i >> 2) + 4 * kq + (i & 3);
                    int chp = (p2 >> 2) ^ ((k >> 3) & 3);
                    int off = k * 20 + (chp << 2) + (p2 & 3);
                    ahi_[off] = pair_hi(av, pav);
                    alo_[off] = pair_hi(lo_part(av), lo_part(pav));
                }
            }
        }
        __syncthreads();   // (4) packed a ready

        // ---- phase C: accC[k][c] += a_scaled · x (3-term split) ----
        {
            U4S8 ah[4], al[4];
            #pragma unroll
            for (int mt = 0; mt < 4; ++mt) {
                int ar = mt * 16 + mrow;
                int chp = kq ^ ((ar >> 3) & 3);
                int idx = ar * 20 + (chp << 2);
                ah[mt].u4 = *(const uint4*)(ahi_ + idx);
                al[mt].u4 = *(const uint4*)(alo_ + idx);
            }
            #pragma unroll
            for (int ntl = 0; ntl < 2; ++ntl) {
                int cr = (2 * wv + ntl) * 16 + mrow;
                int xi = cr * 20 + kq * 4;
                U4S8 xh, xl2;
                xh.u4  = *(const uint4*)(xthi + xi);
                xl2.u4 = *(const uint4*)(xtlo + xi);
                #pragma unroll
                for (int mt = 0; mt < 4; ++mt) {
                    accC[mt][ntl] = MFMA16(ah[mt].s, xh.s,  accC[mt][ntl]);
                    accC[mt][ntl] = MFMA16(ah[mt].s, xl2.s, accC[mt][ntl]);
                    accC[mt][ntl] = MFMA16(al[mt].s, xh.s,  accC[mt][ntl]);
                }
            }
        }
    }

    __syncthreads();
    // ---- asum: reduce over the wave's 16 columns, stage per (ntp,k) ----
    #pragma unroll
    for (int i = 0; i < 8; ++i) {
        asum_acc[i] += __shfl_xor(asum_acc[i], 1);
        asum_acc[i] += __shfl_xor(asum_acc[i], 2);
        asum_acc[i] += __shfl_xor(asum_acc[i], 4);
        asum_acc[i] += __shfl_xor(asum_acc[i], 8);
    }
    if (mrow == 0) {
        #pragma unroll
        for (int i = 0; i < 8; ++i) {
            int k = 32 * mth + 16 * (i >> 2) + 4 * kq + (i & 3);
            fredw[ntp * K_ + k] = asum_acc[i];
        }
    }
    // ---- flush accC (D layout: m = mt*16+kq*4+r, n = (2wv+ntl)*16+mrow) ----
    if (!use_atomic) {
        float* dst = acc_part + (size_t)blockIdx.x * K_ * C_;
        #pragma unroll
        for (int mt = 0; mt < 4; ++mt)
            #pragma unroll
            for (int r = 0; r < 4; ++r)
                #pragma unroll
                for (int ntl = 0; ntl < 2; ++ntl)
                    dst[(mt * 16 + kq * 4 + r) * C_ + (2 * wv + ntl) * 16 + mrow] =
                        accC[mt][ntl][r];
    } else {
        float* dst = acc_part + (size_t)n * K_ * C_;
        #pragma unroll
        for (int mt = 0; mt < 4; ++mt)
            #pragma unroll
            for (int r = 0; r < 4; ++r)
                #pragma unroll
                for (int ntl = 0; ntl < 2; ++ntl)
                    atomicAdd(dst + (mt * 16 + kq * 4 + r) * C_ + (2 * wv + ntl) * 16 + mrow,
                              accC[mt][ntl][r]);
    }
    __syncthreads();
    if (t < K_) {
        float v = fredw[t] + fredw[K_ + t];
        if (use_atomic) atomicAdd(asum_part + n * K_ + t, v);
        else            asum_part[(size_t)blockIdx.x * K_ + t] = v;
    }
}

// ---------------------------------------------------------------------------
// Finalize: reduce npart slices, vlad = acc - asum*centroid, intra-norm over C,
// global norm, store. One block per n; thread t owns (k=t/4, c-quarter=t%4).
// ---------------------------------------------------------------------------
__global__ __launch_bounds__(256, 4)
void netvlad_finalize(const float* __restrict__ acc_part,
                      const float* __restrict__ asum_part,
                      const float* __restrict__ centroids,
                      float* __restrict__ out,
                      int npart)
{
    __shared__ float wred[4];
    const int t = threadIdx.x;
    const int n = blockIdx.x;
    const int k = t >> 2;
    const int part = t & 3;

    float a_k = 0.f;
    for (int s = 0; s < npart; ++s)
        a_k += asum_part[(size_t)(n * npart + s) * K_ + k];

    float4 vals[8];
    #pragma unroll
    for (int i = 0; i < 8; ++i) vals[i] = make_float4(0.f, 0.f, 0.f, 0.f);
    for (int s = 0; s < npart; ++s) {
        const float4* av = (const float4*)(acc_part
            + ((size_t)(n * npart + s) * K_ + k) * C_ + part * 32);
        #pragma unroll
        for (int i = 0; i < 8; ++i) {
            float4 a = av[i];
            vals[i].x += a.x; vals[i].y += a.y;
            vals[i].z += a.z; vals[i].w += a.w;
        }
    }

    const float4* cenv = (const float4*)(centroids + k * C_ + part * 32);
    float loc = 0.f;
    #pragma unroll
    for (int i = 0; i < 8; ++i) {
        float4 cv = cenv[i];
        float4 v = vals[i];
        v.x -= a_k * cv.x; v.y -= a_k * cv.y;
        v.z -= a_k * cv.z; v.w -= a_k * cv.w;
        vals[i] = v;
        loc += v.x * v.x + v.y * v.y + v.z * v.z + v.w * v.w;
    }
    loc += __shfl_xor(loc, 1);
    loc += __shfl_xor(loc, 2);
    float rk = 1.f / fmaxf(sqrtf(loc), 1e-12f);

    float tot = 0.f;
    #pragma unroll
    for (int i = 0; i < 8; ++i) {
        float4 v = vals[i];
        v.x *= rk; v.y *= rk; v.z *= rk; v.w *= rk;
        vals[i] = v;
        tot += v.x * v.x + v.y * v.y + v.z * v.z + v.w * v.w;
    }
    #pragma unroll
    for (int o = 1; o < 64; o <<= 1) tot += __shfl_xor(tot, o);
    if ((t & 63) == 0) wred[t >> 6] = tot;
    __syncthreads();
    float T = wred[0] + wred[1] + wred[2] + wred[3];
    float rtot = 1.f / fmaxf(sqrtf(T), 1e-12f);

    float4* outv = (float4*)(out + ((size_t)n * K_ + k) * C_ + part * 32);
    #pragma unroll
    for (int i = 0; i < 8; ++i) {
        float4 v = vals[i];
        v.x *= rtot; v.y *= rtot; v.z *= rtot; v.w *= rtot;
        outv[i] = v;
    }
}

extern "C" void kernel_launch(void* const* d_in, const int* in_sizes, int n_in,
                              void* d_out, int out_size, void* d_ws, size_t ws_size,
                              hipStream_t stream)
{
    const float* x      = (const float*)d_in[0];
    // d_in[1] = xyz — unused by the reference computation
    const float* cent   = (const float*)d_in[2];
    const float* conv_w = (const float*)d_in[3];
    const float* conv_b = (const float*)d_in[4];
    float* out = (float*)d_out;

    const int nblk = N_ * TILES_PER_N;   // 512
    size_t need = (size_t)nblk * K_ * C_ * sizeof(float)
                + (size_t)nblk * K_ * sizeof(float);
    int use_atomic = (ws_size >= need) ? 0 : 1;
    int npart = use_atomic ? 1 : TILES_PER_N;

    float* acc_part  = (float*)d_ws;
    float* asum_part = acc_part + (size_t)(use_atomic ? N_ : nblk) * K_ * C_;

    if (use_atomic) {
        size_t zbytes = ((size_t)N_ * K_ * C_ + (size_t)N_ * K_) * sizeof(float);
        hipMemsetAsync(d_ws, 0, zbytes, stream);
    }

    hipLaunchKernelGGL(netvlad_main, dim3(nblk), dim3(256), 0, stream,
                       x, conv_w, conv_b, acc_part, asum_part, use_atomic);
    hipLaunchKernelGGL(netvlad_finalize, dim3(N_), dim3(256), 0, stream,
                       acc_part, asum_part, cent, out, npart);
}